// Round 12
// baseline (80.904 us; speedup 1.0000x reference)
//
#include <hip/hip_runtime.h>

// CorrelationCost (tfa): out[b, dy*9+dx, y, x] =
//   (1/128) * sum_c prv[b,c,y,x] * nxt[b,c,y+dy-4,x+dx-4], zero-padded.
// B=4, C=128, H=128, W=256 -> out [4, 81, 128, 256] fp32.
//
// R11 -> R12: chunk turnaround was the constant cost (R10/R11 identical at
// ~66 despite different schedules). (1) CK=32: 4 chunks, 36 MFMA + 24 b64
// frag reads per wave per barrier pair. (2) b64 staging writes (4-ch loads,
// uint2 pk-pairs): 12 b64/thread vs 24 b32. (3) STR=18 u32: b64 frags hit
// all 16 even banks; everything 8B-aligned. (4) 50.8 KB LDS -> 3 blocks/CU.
// Compute/epilogue mapping identical to R10/R11 (verified, absmax 2e-3).

#define SR 4
#define ND 9
#define BB 4
#define CC 128
#define HH 128
#define WW 256
#define HW (HH * WW)

#define YT 4            // y rows per block
#define XT 32           // x px per block
#define NR 12           // N rows staged
#define NW 48           // N px staged (x0-8 .. x0+39)
#define STR 18          // u32 per px: 16 cp + 2 pad
#define PRS (XT * STR + 2)   // 578
#define NRS (NW * STR + 2)   // 866
#define POFF 0
#define NOFF (YT * PRS)      // 2312
#define TOTL (NOFF + NR * NRS)   // 12704 u32 = 50816 B
#define OLSZ (81 * YT * XT)      // 10368 u32 (epilogue scratch, fits in TOTL)

typedef __fp16 h2 __attribute__((ext_vector_type(2)));
typedef __fp16 h4 __attribute__((ext_vector_type(4)));
typedef float f32x4 __attribute__((ext_vector_type(4)));

static __device__ __forceinline__ h2 pk(float lo, float hi) {
    return __builtin_amdgcn_cvt_pkrtz(lo, hi);
}
static __device__ __forceinline__ unsigned as_u32(h2 h) {
    union { h2 h; unsigned u; } v; v.h = h; return v.u;
}
static __device__ __forceinline__ h4 as_h4(uint2 u) {
    union { uint2 u; h4 h; } v; v.u = u; return v.h;
}

__global__ __launch_bounds__(512, 2) void costvol_kernel(
    const float* __restrict__ prv,
    const float* __restrict__ nxt,
    float* __restrict__ out)
{
    __shared__ unsigned shraw[TOTL];

    // XCD-chunked bijective swizzle (1024 % 8 == 0).
    const int nwg  = gridDim.x;
    const int cpx  = nwg >> 3;
    const int orig = blockIdx.x;
    const int wid  = (orig & 7) * cpx + (orig >> 3);

    // x-tile fastest: neighbor blocks share N rows in L2.
    const int xt = wid & 7;
    const int yt = (wid >> 3) & 31;
    const int b  = wid >> 8;
    const int x0 = xt << 5;
    const int y0 = yt << 2;

    const int tid  = threadIdx.x;
    const int w    = tid >> 6;
    const int lane = tid & 63;
    const int li   = lane & 15;
    const int kg   = lane >> 4;          // k-group 0..3

    const int y2 = w & 1;                // y-pair
    const int s  = (w >> 1) & 1;         // A subtile (16 px)
    const int g  = w >> 2;               // B tile parity
    const int ts = s + g;                // B tile index 0..2

    // ---- staging roles: waves 0..5 stage N, waves 6..7 stage P ----
    const int n_cpp = tid & 7;           // cp-pair -> ch 4*cpp..4*cpp+3
    const int n_u   = tid >> 3;          // 0..47
    const int n_q   = n_u >> 2;          // px quad 0..11
    const int n_rb  = n_u & 3;
    const int n_xg  = x0 - 8 + (n_q << 2);
    const bool n_xok = (n_xg >= 0) && (n_xg + 3 < WW);

    const int pt    = tid - 384;
    const int p_cpp = pt & 7;
    const int p_v   = pt >> 3;           // 0..15
    const int p_y   = p_v & 3;
    const int p_qb  = p_v >> 2;          // 0..3

    float4 rv[12];                        // in-flight loads (T14)

    auto issue = [&](int ck) {
        const int c0 = ck << 5;
        if (tid < 384) {
            const float* bp = nxt + (size_t)(b * CC + c0 + 4 * n_cpp) * HW + n_xg;
            #pragma unroll
            for (int it = 0; it < 3; ++it) {
                const int rg = y0 + n_rb + (it << 2) - SR;
                if (n_xok && (unsigned)rg < (unsigned)HH) {
                    const float* sr = bp + (size_t)rg * WW;
                    rv[4 * it + 0] = *(const float4*)sr;
                    rv[4 * it + 1] = *(const float4*)(sr + HW);
                    rv[4 * it + 2] = *(const float4*)(sr + 2 * HW);
                    rv[4 * it + 3] = *(const float4*)(sr + 3 * HW);
                } else {
                    rv[4 * it + 0] = make_float4(0.f, 0.f, 0.f, 0.f);
                    rv[4 * it + 1] = make_float4(0.f, 0.f, 0.f, 0.f);
                    rv[4 * it + 2] = make_float4(0.f, 0.f, 0.f, 0.f);
                    rv[4 * it + 3] = make_float4(0.f, 0.f, 0.f, 0.f);
                }
            }
        } else {
            const float* sp = prv + (size_t)(b * CC + c0 + 4 * p_cpp) * HW + (y0 + p_y) * WW + x0;
            #pragma unroll
            for (int it = 0; it < 2; ++it) {
                const int xq = (p_qb + (it << 2)) << 2;
                rv[4 * it + 0] = *(const float4*)(sp + xq);
                rv[4 * it + 1] = *(const float4*)(sp + xq + HW);
                rv[4 * it + 2] = *(const float4*)(sp + xq + 2 * HW);
                rv[4 * it + 3] = *(const float4*)(sp + xq + 3 * HW);
            }
        }
    };

    auto commit = [&]() {
        if (tid < 384) {
            #pragma unroll
            for (int it = 0; it < 3; ++it) {
                const int row = n_rb + (it << 2);
                unsigned* d = shraw + NOFF + row * NRS + (n_q << 2) * STR + 2 * n_cpp;
                const float4 v0 = rv[4 * it + 0], v1 = rv[4 * it + 1];
                const float4 v2 = rv[4 * it + 2], v3 = rv[4 * it + 3];
                *(uint2*)(d + 0 * STR) = make_uint2(as_u32(pk(v0.x, v1.x)), as_u32(pk(v2.x, v3.x)));
                *(uint2*)(d + 1 * STR) = make_uint2(as_u32(pk(v0.y, v1.y)), as_u32(pk(v2.y, v3.y)));
                *(uint2*)(d + 2 * STR) = make_uint2(as_u32(pk(v0.z, v1.z)), as_u32(pk(v2.z, v3.z)));
                *(uint2*)(d + 3 * STR) = make_uint2(as_u32(pk(v0.w, v1.w)), as_u32(pk(v2.w, v3.w)));
            }
        } else {
            #pragma unroll
            for (int it = 0; it < 2; ++it) {
                const int xq = (p_qb + (it << 2)) << 2;
                unsigned* d = shraw + POFF + p_y * PRS + xq * STR + 2 * p_cpp;
                const float4 v0 = rv[4 * it + 0], v1 = rv[4 * it + 1];
                const float4 v2 = rv[4 * it + 2], v3 = rv[4 * it + 3];
                *(uint2*)(d + 0 * STR) = make_uint2(as_u32(pk(v0.x, v1.x)), as_u32(pk(v2.x, v3.x)));
                *(uint2*)(d + 1 * STR) = make_uint2(as_u32(pk(v0.y, v1.y)), as_u32(pk(v2.y, v3.y)));
                *(uint2*)(d + 2 * STR) = make_uint2(as_u32(pk(v0.z, v1.z)), as_u32(pk(v2.z, v3.z)));
                *(uint2*)(d + 3 * STR) = make_uint2(as_u32(pk(v0.w, v1.w)), as_u32(pk(v2.w, v3.w)));
            }
        }
    };

    f32x4 acc0[ND], acc1[ND];
    #pragma unroll
    for (int dy = 0; dy < ND; ++dy) {
        acc0[dy] = (f32x4){0.f, 0.f, 0.f, 0.f};
        acc1[dy] = (f32x4){0.f, 0.f, 0.f, 0.f};
    }

    auto compute = [&]() {
        const unsigned* L = shraw;
        h4 a0[2], a1[2];
        #pragma unroll
        for (int kh = 0; kh < 2; ++kh) {
            const int ko = (kh << 3) + (kg << 1);
            a0[kh] = as_h4(*(const uint2*)(L + POFF + (2 * y2 + 0) * PRS + ((s << 4) + li) * STR + ko));
            a1[kh] = as_h4(*(const uint2*)(L + POFF + (2 * y2 + 1) * PRS + ((s << 4) + li) * STR + ko));
        }
        const unsigned* NB = L + NOFF + ((ts << 4) + li) * STR;
        h4 bp0 = as_h4(*(const uint2*)(NB + (2 * y2) * NRS + 0 + (kg << 1)));
        h4 bp1 = as_h4(*(const uint2*)(NB + (2 * y2) * NRS + 8 + (kg << 1)));
        #pragma unroll
        for (int dy = 0; dy < ND; ++dy) {
            const unsigned* R = NB + (2 * y2 + dy + 1) * NRS;
            const h4 bn0 = as_h4(*(const uint2*)(R + 0 + (kg << 1)));
            const h4 bn1 = as_h4(*(const uint2*)(R + 8 + (kg << 1)));
            acc0[dy] = __builtin_amdgcn_mfma_f32_16x16x16f16(a0[0], bp0, acc0[dy], 0, 0, 0);
            acc0[dy] = __builtin_amdgcn_mfma_f32_16x16x16f16(a0[1], bp1, acc0[dy], 0, 0, 0);
            acc1[dy] = __builtin_amdgcn_mfma_f32_16x16x16f16(a1[0], bn0, acc1[dy], 0, 0, 0);
            acc1[dy] = __builtin_amdgcn_mfma_f32_16x16x16f16(a1[1], bn1, acc1[dy], 0, 0, 0);
            bp0 = bn0; bp1 = bn1;
        }
    };

    // ---- pipelined chunk loop: 4 chunks of 32 channels ----
    issue(0);
    commit();
    __syncthreads();
    for (int ck = 0; ck < 4; ++ck) {
        if (ck < 3) issue(ck + 1);      // loads in flight during compute
        compute();
        __syncthreads();                // buffer reads done
        if (ck < 3) {
            commit();                   // vmcnt wait lands post-compute
            __syncthreads();            // writes visible
        }
    }

    // ---- epilogue: scatter -> LDS, then coalesced float4 stores ----
    float* Ol = (float*)shraw;
    const float invc = 1.0f / (float)CC;
    #pragma unroll
    for (int dy = 0; dy < ND; ++dy) {
        #pragma unroll
        for (int r = 0; r < 4; ++r) {
            const int m  = (kg << 2) + r;
            const int px = (s << 4) + m;
            const int dx = (g << 4) + li - m - SR;
            if ((unsigned)dx < 9u) {
                const int comb = dy * ND + dx;
                Ol[((comb << 2) + (y2 << 1) + 0) * XT + px] = acc0[dy][r] * invc;
                Ol[((comb << 2) + (y2 << 1) + 1) * XT + px] = acc1[dy][r] * invc;
            }
        }
    }
    __syncthreads();
    #pragma unroll
    for (int it = 0; it < 6; ++it) {
        const int c = tid + (it << 9);
        if (c < (81 * YT * XT) / 4) {          // 2592 float4 chunks
            const int px4  = c & 7;
            const int y    = (c >> 3) & 3;
            const int comb = c >> 5;
            const float4 v = *(const float4*)&Ol[c << 2];
            *(float4*)(out + ((size_t)(b * 81 + comb) * HH + (y0 + y)) * WW + x0 + (px4 << 2)) = v;
        }
    }
}

extern "C" void kernel_launch(void* const* d_in, const int* in_sizes, int n_in,
                              void* d_out, int out_size, void* d_ws, size_t ws_size,
                              hipStream_t stream) {
    const float* prv = (const float*)d_in[0];
    const float* nxt = (const float*)d_in[1];
    float* out = (float*)d_out;

    const int nblocks = BB * (HH / YT) * (WW / XT);  // 4 * 32 * 8 = 1024
    costvol_kernel<<<nblocks, 512, 0, stream>>>(prv, nxt, out);
}

// Round 13
// 60.749 us; speedup vs baseline: 1.3318x; 1.3318x over previous
//
#include <hip/hip_runtime.h>

// CorrelationCost (tfa): out[b, dy*9+dx, y, x] =
//   (1/128) * sum_c prv[b,c,y,x] * nxt[b,c,y+dy-4,x+dx-4], zero-padded.
// B=4, C=128, H=128, W=256 -> out [4, 81, 128, 256] fp32.
//
// R13: dy-triplet dot2. Block = (b, y-pair, dy-group of 3 consecutive);
// wave = one y row, all 128 channels, 3 dy accumulators (27 dx-dy combos x
// 4 px = 108 f32). Cuts global re-reads 9x -> 3x (1.18 GB -> 786 MB) and
// triples compute per load. nxt rows staged in wave-private padded LDS rows
// (double-buffered, CFENCE discipline from R7 -- NO barriers); own-quad kept
// in registers so windows cost only 6 ds_read_b128 + 3 writes per pair.
// 768 blocks x 128 thr: all blocks co-resident (3/CU x 2 waves at ~190 VGPR).

#define SR 4
#define ND 9
#define BB 4
#define CC 128
#define HH 128
#define WW 256
#define HW (HH * WW)
#define PADW 264      // 4 left pad + 256 px + 4 right pad (u32 = h2 pair)

typedef __fp16 h2 __attribute__((ext_vector_type(2)));

static __device__ __forceinline__ h2 pk(float lo, float hi) {
    return __builtin_amdgcn_cvt_pkrtz(lo, hi);   // v_cvt_pkrtz_f16_f32
}
static __device__ __forceinline__ h2 as_h2(unsigned u) {
    union { unsigned u; h2 h; } v; v.u = u; return v.h;
}
static __device__ __forceinline__ unsigned as_u32(h2 h) {
    union { unsigned u; h2 h; } v; v.h = h; return v.u;
}

#define CFENCE asm volatile("" ::: "memory")

__global__ __launch_bounds__(128, 2) void costvol_kernel(
    const float* __restrict__ prv,
    const float* __restrict__ nxt,
    float* __restrict__ out)
{
    // [wave][buf][row j][padded row] = 2*2*3*264*4 = 12672 B
    __shared__ unsigned lds[2][2][3][PADW];

    // XCD-chunked bijective swizzle (768 % 8 == 0).
    const int nwg  = gridDim.x;
    const int cpx  = nwg >> 3;                 // 96
    const int orig = blockIdx.x;
    const int wid  = (orig & 7) * cpx + (orig >> 3);

    // g fastest: the 3 dy-groups sharing (b, y-pair) are L2-local.
    const int g  = wid % 3;
    const int r_ = wid / 3;
    const int yp = r_ & 63;
    const int b  = r_ >> 6;

    const int tid  = threadIdx.x;
    const int w    = tid >> 6;                 // wave 0..1 = y row in pair
    const int lane = tid & 63;
    const int x0   = lane << 2;                // 4 px per lane
    const int y    = (yp << 1) + w;
    const int r0   = y + 3 * g - SR;           // first of 3 consecutive nxt rows

    bool vok[3];
    #pragma unroll
    for (int j = 0; j < 3; ++j)
        vok[j] = ((unsigned)(r0 + j) < (unsigned)HH);

    const float* pg = prv + (size_t)b * CC * HW + (size_t)y * WW + x0;
    const float* ng = nxt + (size_t)b * CC * HW + x0 + (ptrdiff_t)r0 * WW;

    // Zero the 4-u32 pads: 2 buf x 3 rows x 2 ends = 12 per wave, once.
    if (lane < 12) {
        const int e  = lane >= 6;
        const int t  = lane - (e ? 6 : 0);
        const int bf = t & 1;
        const int j  = t >> 1;
        *reinterpret_cast<uint4*>(&lds[w][bf][j][e ? 260 : 0]) =
            make_uint4(0u, 0u, 0u, 0u);
    }

    float acc[3][ND][4];
    #pragma unroll
    for (int j = 0; j < 3; ++j)
        #pragma unroll
        for (int dx = 0; dx < ND; ++dx)
            #pragma unroll
            for (int px = 0; px < 4; ++px)
                acc[j][dx][px] = 0.f;

    // Load one channel-pair: p (2 float4) + n (3 rows x 2 ch = 6 float4).
    #define LOADP(k, P0, P1, N) do { \
        const float* pp_ = pg + (size_t)(2 * (k)) * HW; \
        P0 = *reinterpret_cast<const float4*>(pp_); \
        P1 = *reinterpret_cast<const float4*>(pp_ + HW); \
        const float* nn_ = ng + (size_t)(2 * (k)) * HW; \
        _Pragma("unroll") \
        for (int j_ = 0; j_ < 3; ++j_) { \
            if (vok[j_]) { \
                N[j_][0] = *reinterpret_cast<const float4*>(nn_ + j_ * WW); \
                N[j_][1] = *reinterpret_cast<const float4*>(nn_ + j_ * WW + HW); \
            } else { \
                N[j_][0] = make_float4(0.f, 0.f, 0.f, 0.f); \
                N[j_][1] = make_float4(0.f, 0.f, 0.f, 0.f); \
            } \
        } } while (0)

    #define PKN(NH, N) do { \
        _Pragma("unroll") \
        for (int j_ = 0; j_ < 3; ++j_) { \
            NH[j_][0] = as_u32(pk(N[j_][0].x, N[j_][1].x)); \
            NH[j_][1] = as_u32(pk(N[j_][0].y, N[j_][1].y)); \
            NH[j_][2] = as_u32(pk(N[j_][0].z, N[j_][1].z)); \
            NH[j_][3] = as_u32(pk(N[j_][0].w, N[j_][1].w)); \
        } } while (0)

    #define STAGE(bf, NH) do { \
        _Pragma("unroll") \
        for (int j_ = 0; j_ < 3; ++j_) \
            *reinterpret_cast<uint4*>(&lds[w][bf][j_][4 + x0]) = \
                make_uint4(NH[j_][0], NH[j_][1], NH[j_][2], NH[j_][3]); \
        } while (0)

    float4 P0c, P1c, P0n, P1n, Nc[3][2], Nn[3][2];
    unsigned nhc[3][4], nhn[3][4];

    // Prologue: pair 0 loaded, packed, staged to buf0.
    LOADP(0, P0c, P1c, Nc);
    PKN(nhc, Nc);
    STAGE(0, nhc);
    CFENCE;

    for (int k = 0; k < 64; ++k) {
        const int bf = k & 1;
        if (k < 63) LOADP(k + 1, P0n, P1n, Nn);   // in flight during dots

        h2 ph[4];
        ph[0] = pk(P0c.x, P1c.x); ph[1] = pk(P0c.y, P1c.y);
        ph[2] = pk(P0c.z, P1c.z); ph[3] = pk(P0c.w, P1c.w);

        #pragma unroll
        for (int j = 0; j < 3; ++j) {
            const uint4 wl = *reinterpret_cast<const uint4*>(&lds[w][bf][j][x0]);
            const uint4 wr = *reinterpret_cast<const uint4*>(&lds[w][bf][j][x0 + 8]);
            h2 n12[12];
            n12[0] = as_h2(wl.x); n12[1] = as_h2(wl.y);
            n12[2] = as_h2(wl.z); n12[3] = as_h2(wl.w);
            n12[4] = as_h2(nhc[j][0]); n12[5] = as_h2(nhc[j][1]);
            n12[6] = as_h2(nhc[j][2]); n12[7] = as_h2(nhc[j][3]);
            n12[8] = as_h2(wr.x); n12[9] = as_h2(wr.y);
            n12[10] = as_h2(wr.z); n12[11] = as_h2(wr.w);
            #pragma unroll
            for (int dx = 0; dx < ND; ++dx)
                #pragma unroll
                for (int px = 0; px < 4; ++px)
                    acc[j][dx][px] =
                        __builtin_amdgcn_fdot2(ph[px], n12[dx + px], acc[j][dx][px], false);
        }

        if (k < 63) {
            PKN(nhn, Nn);                    // vmcnt wait lands here, post-dots
            STAGE(bf ^ 1, nhn);
            CFENCE;                          // next iter's reads stay below
            P0c = P0n; P1c = P1n;
            #pragma unroll
            for (int j = 0; j < 3; ++j)
                #pragma unroll
                for (int i = 0; i < 4; ++i)
                    nhc[j][i] = nhn[j][i];
        }
    }

    // Epilogue: direct coalesced float4 stores (wave owns full channel sum).
    const float invc = 1.0f / (float)CC;
    #pragma unroll
    for (int j = 0; j < 3; ++j) {
        const int dy = 3 * g + j;
        #pragma unroll
        for (int dx = 0; dx < ND; ++dx) {
            float* op = out + ((size_t)(b * 81 + dy * ND + dx) * HH + y) * WW + x0;
            *reinterpret_cast<float4*>(op) =
                make_float4(acc[j][dx][0] * invc, acc[j][dx][1] * invc,
                            acc[j][dx][2] * invc, acc[j][dx][3] * invc);
        }
    }
}

extern "C" void kernel_launch(void* const* d_in, const int* in_sizes, int n_in,
                              void* d_out, int out_size, void* d_ws, size_t ws_size,
                              hipStream_t stream) {
    const float* prv = (const float*)d_in[0];
    const float* nxt = (const float*)d_in[1];
    float* out = (float*)d_out;

    const int nblocks = BB * (HH / 2) * 3;   // 4 * 64 * 3 = 768
    costvol_kernel<<<nblocks, 128, 0, stream>>>(prv, nxt, out);
}

// Round 14
// 51.130 us; speedup vs baseline: 1.5823x; 1.1881x over previous
//
#include <hip/hip_runtime.h>

// CorrelationCost (tfa): out[b, dy*9+dx, y, x] =
//   (1/128) * sum_c prv[b,c,y,x] * nxt[b,c,y+dy-4,x+dx-4], zero-padded.
// B=4, C=128, H=128, W=256 -> out [4, 81, 128, 256] fp32.
//
// R13 -> R14: R13 (dy-triplet, 3x traffic cut) was occupancy-starved
// (6 waves/CU). Hybrid: block = (b, y-pair, dy-triplet), 4 waves =
// 2 rows x 2 channel-halves (32 pairs each) -> 768 blocks x 4 waves =
// 12 waves/CU, exactly co-resident. Main loop = R13's verified CFENCE
// pipeline (wave-private staging, no barriers). Epilogue: c-half LDS
// reduction in 3 dy-chunks (stride-40 pad), then coalesced stores.

#define SR 4
#define ND 9
#define BB 4
#define CC 128
#define HH 128
#define WW 256
#define HW (HH * WW)
#define PADW 264      // 4 left pad + 256 px + 4 right pad (u32 = h2 pair)
#define RSTR 40       // reduction lane stride (u32): 16B-aligned, 4-way max

typedef __fp16 h2 __attribute__((ext_vector_type(2)));

static __device__ __forceinline__ h2 pk(float lo, float hi) {
    return __builtin_amdgcn_cvt_pkrtz(lo, hi);   // v_cvt_pkrtz_f16_f32
}
static __device__ __forceinline__ h2 as_h2(unsigned u) {
    union { unsigned u; h2 h; } v; v.u = u; return v.h;
}
static __device__ __forceinline__ unsigned as_u32(h2 h) {
    union { unsigned u; h2 h; } v; v.h = h; return v.u;
}

#define CFENCE asm volatile("" ::: "memory")

__global__ __launch_bounds__(256, 3) void costvol_kernel(
    const float* __restrict__ prv,
    const float* __restrict__ nxt,
    float* __restrict__ out)
{
    // staging: [4 waves][2 bufs][3 rows][PADW] = 6336 u32 = 25344 B
    // reduction union: 128 lanes * RSTR(40) = 5120 u32 (staging dead by then)
    __shared__ unsigned shraw[4 * 2 * 3 * PADW];

    // XCD-chunked bijective swizzle (768 % 8 == 0).
    const int nwg  = gridDim.x;
    const int cpx  = nwg >> 3;                 // 96
    const int orig = blockIdx.x;
    const int wid  = (orig & 7) * cpx + (orig >> 3);

    // g fastest: the 3 dy-groups sharing (b, y-pair) are L2-local.
    const int g  = wid % 3;
    const int r_ = wid / 3;
    const int yp = r_ & 63;
    const int b  = r_ >> 6;

    const int tid  = threadIdx.x;
    const int w    = tid >> 6;                 // wave 0..3
    const int lane = tid & 63;
    const int ry   = w & 1;                    // y row in pair
    const int ch   = w >> 1;                   // channel half
    const int x0   = lane << 2;                // 4 px per lane
    const int y    = (yp << 1) + ry;
    const int r0   = y + 3 * g - SR;           // first of 3 nxt rows

    bool vok[3];
    #pragma unroll
    for (int j = 0; j < 3; ++j)
        vok[j] = ((unsigned)(r0 + j) < (unsigned)HH);

    unsigned* stg = shraw + w * (2 * 3 * PADW);   // wave-private staging

    // Zero the 4-u32 pads: 2 buf x 3 rows x 2 ends = 12 per wave, once.
    if (lane < 12) {
        const int e  = lane >= 6 ? 1 : 0;
        const int q  = lane - 6 * e;
        const int bf = q & 1;
        const int j  = q >> 1;
        *reinterpret_cast<uint4*>(stg + (bf * 3 + j) * PADW + (e ? 260 : 0)) =
            make_uint4(0u, 0u, 0u, 0u);
    }

    const size_t cbase = (size_t)(b * CC + (ch << 6)) * HW;
    const float* pg = prv + cbase + (size_t)y * WW + x0;
    const float* ng = nxt + cbase + (ptrdiff_t)r0 * WW + x0;

    float acc[3][ND][4];
    #pragma unroll
    for (int j = 0; j < 3; ++j)
        #pragma unroll
        for (int dx = 0; dx < ND; ++dx)
            #pragma unroll
            for (int px = 0; px < 4; ++px)
                acc[j][dx][px] = 0.f;

    #define LOADP(k, P0, P1, N) do { \
        const float* pp_ = pg + (size_t)(2 * (k)) * HW; \
        P0 = *reinterpret_cast<const float4*>(pp_); \
        P1 = *reinterpret_cast<const float4*>(pp_ + HW); \
        const float* nn_ = ng + (size_t)(2 * (k)) * HW; \
        _Pragma("unroll") \
        for (int j_ = 0; j_ < 3; ++j_) { \
            if (vok[j_]) { \
                N[j_][0] = *reinterpret_cast<const float4*>(nn_ + j_ * WW); \
                N[j_][1] = *reinterpret_cast<const float4*>(nn_ + j_ * WW + HW); \
            } else { \
                N[j_][0] = make_float4(0.f, 0.f, 0.f, 0.f); \
                N[j_][1] = make_float4(0.f, 0.f, 0.f, 0.f); \
            } \
        } } while (0)

    #define PKN(NH, N) do { \
        _Pragma("unroll") \
        for (int j_ = 0; j_ < 3; ++j_) { \
            NH[j_][0] = as_u32(pk(N[j_][0].x, N[j_][1].x)); \
            NH[j_][1] = as_u32(pk(N[j_][0].y, N[j_][1].y)); \
            NH[j_][2] = as_u32(pk(N[j_][0].z, N[j_][1].z)); \
            NH[j_][3] = as_u32(pk(N[j_][0].w, N[j_][1].w)); \
        } } while (0)

    #define STAGE(bf, NH) do { \
        _Pragma("unroll") \
        for (int j_ = 0; j_ < 3; ++j_) \
            *reinterpret_cast<uint4*>(stg + ((bf) * 3 + j_) * PADW + 4 + x0) = \
                make_uint4(NH[j_][0], NH[j_][1], NH[j_][2], NH[j_][3]); \
        } while (0)

    float4 P0c, P1c, P0n, P1n, Nc[3][2], Nn[3][2];
    unsigned nhc[3][4], nhn[3][4];

    // Prologue: pair 0 loaded, packed, staged to buf0.
    LOADP(0, P0c, P1c, Nc);
    PKN(nhc, Nc);
    STAGE(0, nhc);
    CFENCE;

    for (int k = 0; k < 32; ++k) {
        const int bf = k & 1;
        if (k < 31) LOADP(k + 1, P0n, P1n, Nn);   // in flight during dots

        h2 ph[4];
        ph[0] = pk(P0c.x, P1c.x); ph[1] = pk(P0c.y, P1c.y);
        ph[2] = pk(P0c.z, P1c.z); ph[3] = pk(P0c.w, P1c.w);

        #pragma unroll
        for (int j = 0; j < 3; ++j) {
            const unsigned* row = stg + (bf * 3 + j) * PADW;
            const uint4 wl = *reinterpret_cast<const uint4*>(row + x0);
            const uint4 wr = *reinterpret_cast<const uint4*>(row + x0 + 8);
            h2 n12[12];
            n12[0] = as_h2(wl.x); n12[1] = as_h2(wl.y);
            n12[2] = as_h2(wl.z); n12[3] = as_h2(wl.w);
            n12[4] = as_h2(nhc[j][0]); n12[5] = as_h2(nhc[j][1]);
            n12[6] = as_h2(nhc[j][2]); n12[7] = as_h2(nhc[j][3]);
            n12[8] = as_h2(wr.x); n12[9] = as_h2(wr.y);
            n12[10] = as_h2(wr.z); n12[11] = as_h2(wr.w);
            #pragma unroll
            for (int dx = 0; dx < ND; ++dx)
                #pragma unroll
                for (int px = 0; px < 4; ++px)
                    acc[j][dx][px] =
                        __builtin_amdgcn_fdot2(ph[px], n12[dx + px], acc[j][dx][px], false);
        }

        if (k < 31) {
            PKN(nhn, Nn);                    // vmcnt wait lands here, post-dots
            STAGE(bf ^ 1, nhn);
            CFENCE;                          // next iter's reads stay below
            P0c = P0n; P1c = P1n;
            #pragma unroll
            for (int j = 0; j < 3; ++j)
                #pragma unroll
                for (int i = 0; i < 4; ++i)
                    nhc[j][i] = nhn[j][i];
        }
    }
    #undef STAGE
    #undef PKN
    #undef LOADP

    // ---- c-half reduction + output, 3 dy-chunks (staging area reused) ----
    const float invc = 1.0f / (float)CC;
    #pragma unroll
    for (int j = 0; j < 3; ++j) {
        __syncthreads();                    // prior chunk reads / loop LDS done
        if (ch == 1) {
            float* red = reinterpret_cast<float*>(shraw) + ((ry << 6) + lane) * RSTR;
            #pragma unroll
            for (int dx = 0; dx < ND; ++dx)
                *reinterpret_cast<float4*>(red + (dx << 2)) =
                    make_float4(acc[j][dx][0], acc[j][dx][1],
                                acc[j][dx][2], acc[j][dx][3]);
        }
        __syncthreads();
        if (ch == 0) {
            const float* red = reinterpret_cast<const float*>(shraw) + ((ry << 6) + lane) * RSTR;
            const int dy = 3 * g + j;
            #pragma unroll
            for (int dx = 0; dx < ND; ++dx) {
                const float4 t = *reinterpret_cast<const float4*>(red + (dx << 2));
                float* op = out + ((size_t)(b * 81 + dy * ND + dx) * HH + y) * WW + x0;
                *reinterpret_cast<float4*>(op) = make_float4(
                    (acc[j][dx][0] + t.x) * invc, (acc[j][dx][1] + t.y) * invc,
                    (acc[j][dx][2] + t.z) * invc, (acc[j][dx][3] + t.w) * invc);
            }
        }
    }
}

extern "C" void kernel_launch(void* const* d_in, const int* in_sizes, int n_in,
                              void* d_out, int out_size, void* d_ws, size_t ws_size,
                              hipStream_t stream) {
    const float* prv = (const float*)d_in[0];
    const float* nxt = (const float*)d_in[1];
    float* out = (float*)d_out;

    const int nblocks = BB * (HH / 2) * 3;   // 4 * 64 * 3 = 768
    costvol_kernel<<<nblocks, 256, 0, stream>>>(prv, nxt, out);
}